// Round 10
// baseline (114.592 us; speedup 1.0000x reference)
//
#include <hip/hip_runtime.h>

#define SLOPE 0.2f

__device__ __forceinline__ float leaky(float v) {
    return __builtin_fmaxf(v, SLOPE * v);
}
__device__ __forceinline__ float fast_tanh(float v) {
    float e = __expf(2.0f * v);
    return 1.0f - 2.0f * __builtin_amdgcn_rcpf(e + 1.0f);
}

// Quad-lane shifts via DPP quad_perm; the 4 lanes of a quad are the 4
// quarters of one sample (verified correct in R9). MUST run under full
// EXEC: compute unconditionally, select after (R4 lesson).
__device__ __forceinline__ float qprev(float v) {   // from lane p-1
    int i = __builtin_bit_cast(int, v);
    i = __builtin_amdgcn_mov_dpp(i, 0x93, 0xF, 0xF, true);
    return __builtin_bit_cast(float, i);
}
__device__ __forceinline__ float qnext(float v) {   // from lane p+1
    int i = __builtin_bit_cast(int, v);
    i = __builtin_amdgcn_mov_dpp(i, 0x39, 0xF, 0xF, true);
    return __builtin_bit_cast(float, i);
}

// R10 theory: five different engines all pinned at ~28-31 us; the one
// invariant was the LDS-staged barrier-phase structure (load->barrier->
// compute->barrier->store, phase-aligned across lockstep blocks). This
// kernel removes LDS and barriers entirely: 4 threads/sample, lane 4k+p
// loads float4s s*8+p and s*8+4+p directly (complementary 64B half-lines,
// 2KB/wave contiguous, L1-served), computes with R9's verified quad-DPP
// body, stores the same pattern. Waves fully independent; grid-stride x2.
__global__ __launch_bounds__(256, 8) void minigen_kernel(
    const float* __restrict__ x,
    const float* __restrict__ w1, const float* __restrict__ b1,
    const float* __restrict__ w2, const float* __restrict__ b2,
    const float* __restrict__ w3, const float* __restrict__ b3,
    const float* __restrict__ w4, const float* __restrict__ b4,
    float* __restrict__ out, int ntasks)
{
    const int tid0 = blockIdx.x * 256 + threadIdx.x;
    const int p = threadIdx.x & 3;               // quarter of the sample
    const int stride = gridDim.x * 256;          // tasks per sweep (mult of 4)
    const float4* xin = (const float4*)x;
    float4* outp = (float4*)out;

#pragma unroll 1
    for (int task = tid0; task < ntasks; task += stride) {
        const int s = task >> 2;                 // sample; task&3 == p

        // ---- direct global -> registers: x[ic][4p..4p+3] ----
        float4 va = xin[s * 8 + p];              // ic=0
        float4 vb = xin[s * 8 + 4 + p];          // ic=1
        float xr[2][4] = {{va.x, va.y, va.z, va.w},
                          {vb.x, vb.y, vb.z, vb.w}};

        // ---- conv1: [2,16] -> [4,8], s2 p1, leaky; own cols l=2p,2p+1 ----
        float xh[2];
#pragma unroll
        for (int ic = 0; ic < 2; ++ic) {
            float h = qprev(xr[ic][3]);          // x[ic][4p-1]
            xh[ic] = p ? h : 0.0f;               // p==0: left pad
        }
        float e1q[4][2];                         // e1[oc][2p+dl]
#pragma unroll
        for (int oc = 0; oc < 4; ++oc) {
#pragma unroll
            for (int dl = 0; dl < 2; ++dl) {
                float s1 = b1[oc];
#pragma unroll
                for (int ic = 0; ic < 2; ++ic)
#pragma unroll
                    for (int k = 0; k < 3; ++k) {
                        int u = 2 * dl - 1 + k;  // [-1..3] compile-time
                        float v = (u < 0) ? xh[ic] : xr[ic][u];
                        s1 = fmaf(v, w1[(oc * 2 + ic) * 3 + k], s1);
                    }
                e1q[oc][dl] = leaky(s1);
            }
        }

        // ---- conv2: [4,8] -> [8,4], s2 p1, leaky; own col = p ----
        float eh[4];
#pragma unroll
        for (int ic = 0; ic < 4; ++ic) {
            float h = qprev(e1q[ic][1]);         // e1[ic][2p-1]
            eh[ic] = p ? h : 0.0f;
        }
        float bn[8];                             // bn[oc][p]
#pragma unroll
        for (int oc = 0; oc < 8; ++oc) {
            float s1 = b2[oc];
#pragma unroll
            for (int ic = 0; ic < 4; ++ic) {
                s1 = fmaf(eh[ic],     w2[(oc * 4 + ic) * 3 + 0], s1);
                s1 = fmaf(e1q[ic][0], w2[(oc * 4 + ic) * 3 + 1], s1);
                s1 = fmaf(e1q[ic][1], w2[(oc * 4 + ic) * 3 + 2], s1);
            }
            bn[oc] = leaky(s1);
        }

        // ---- up1(x2) + conv3: [8,8] -> [4,8], s1 p1, leaky, +skip e1 ----
        float bl[8], br[8];
#pragma unroll
        for (int ic = 0; ic < 8; ++ic) {
            float hl = qprev(bn[ic]);
            float hr = qnext(bn[ic]);
            bl[ic] = p ? hl : 0.0f;              // p==0: u=-1 pad
            br[ic] = (p == 3) ? 0.0f : hr;       // p==3: u=8 pad
        }
        float skq[4][2];                         // sk[oc][2p+dl]
#pragma unroll
        for (int oc = 0; oc < 4; ++oc) {
            float s0 = b3[oc], s1 = b3[oc];
#pragma unroll
            for (int ic = 0; ic < 8; ++ic) {
                const float* wr = w3 + (oc * 8 + ic) * 3;
                s0 = fmaf(bl[ic], wr[0], s0);
                s0 = fmaf(bn[ic], wr[1], s0);
                s0 = fmaf(bn[ic], wr[2], s0);
                s1 = fmaf(bn[ic], wr[0], s1);
                s1 = fmaf(bn[ic], wr[1], s1);
                s1 = fmaf(br[ic], wr[2], s1);
            }
            skq[oc][0] = leaky(s0) + e1q[oc][0];
            skq[oc][1] = leaky(s1) + e1q[oc][1];
        }

        // ---- up2(x2) + conv4: [4,16] -> [2,16], s1 p1, tanh ----
        float sl[4], sr[4];
#pragma unroll
        for (int ic = 0; ic < 4; ++ic) {
            float hl = qprev(skq[ic][1]);        // sk[ic][2p-1]
            float hr = qnext(skq[ic][0]);        // sk[ic][2p+2]
            sl[ic] = p ? hl : 0.0f;
            sr[ic] = (p == 3) ? 0.0f : hr;
        }
        float4 o0, o1;
#pragma unroll
        for (int oc = 0; oc < 2; ++oc) {
            float a0 = b4[oc], a1 = b4[oc], a2 = b4[oc], a3 = b4[oc];
#pragma unroll
            for (int ic = 0; ic < 4; ++ic) {
                const float* wr = w4 + (oc * 4 + ic) * 3;
                float s0 = skq[ic][0], s1 = skq[ic][1];
                a0 = fmaf(sl[ic], wr[0], a0);
                a0 = fmaf(s0,     wr[1], a0);
                a0 = fmaf(s0,     wr[2], a0);
                a1 = fmaf(s0,     wr[0], a1);
                a1 = fmaf(s0,     wr[1], a1);
                a1 = fmaf(s1,     wr[2], a1);
                a2 = fmaf(s0,     wr[0], a2);
                a2 = fmaf(s1,     wr[1], a2);
                a2 = fmaf(s1,     wr[2], a2);
                a3 = fmaf(s1,     wr[0], a3);
                a3 = fmaf(s1,     wr[1], a3);
                a3 = fmaf(sr[ic], wr[2], a3);
            }
            float4 ov = make_float4(fast_tanh(a0), fast_tanh(a1),
                                    fast_tanh(a2), fast_tanh(a3));
            if (oc == 0) o0 = ov; else o1 = ov;
        }

        // ---- direct registers -> global (same pattern as loads) ----
        outp[s * 8 + p]     = o0;                // out[0][4p..4p+3]
        outp[s * 8 + 4 + p] = o1;                // out[1][4p..4p+3]
    }
}

extern "C" void kernel_launch(void* const* d_in, const int* in_sizes, int n_in,
                              void* d_out, int out_size, void* d_ws, size_t ws_size,
                              hipStream_t stream) {
    const float* x  = (const float*)d_in[0];
    const float* w1 = (const float*)d_in[1];
    const float* b1 = (const float*)d_in[2];
    const float* w2 = (const float*)d_in[3];
    const float* b2 = (const float*)d_in[4];
    const float* w3 = (const float*)d_in[5];
    const float* b3 = (const float*)d_in[6];
    const float* w4 = (const float*)d_in[7];
    const float* b4 = (const float*)d_in[8];
    float* out = (float*)d_out;

    int n = in_sizes[0] / 32;            // B = 262144 samples
    int ntasks = n * 4;                  // 4 threads per sample
    int grid = 2048;                     // 8 blocks/CU resident; 2 sweeps
    hipLaunchKernelGGL(minigen_kernel, dim3(grid), dim3(256), 0, stream,
                       x, w1, b1, w2, b2, w3, b3, w4, b4, out, ntasks);
}